// Round 8
// baseline (201.106 us; speedup 1.0000x reference)
//
#include <hip/hip_runtime.h>
#include <math.h>

#define NB 4
#define NC 256
#define NHEADS 4
#define DH 64
#define NT 4096            // 64*64 tokens per batch
// q pre-scale with log2(e) folded in: exp(s/8) == exp2(s * QSCALE)
#define QSCALE (0.125f * 1.44269504088896f)

typedef __bf16  bf16x8 __attribute__((ext_vector_type(8)));
typedef float   f32x4  __attribute__((ext_vector_type(4)));
typedef float   f32x16 __attribute__((ext_vector_type(16)));
typedef short   s16x8  __attribute__((ext_vector_type(8)));
typedef unsigned int u32x4 __attribute__((ext_vector_type(4)));

static __device__ __forceinline__ unsigned short f2bf(float f) {
    unsigned u = __float_as_uint(f);
    u = (u + 0x7fffu + ((u >> 16) & 1u)) >> 16;   // round-to-nearest-even
    return (unsigned short)u;
}

static __device__ __forceinline__ float fast_exp2(float x) {
    return __builtin_amdgcn_exp2f(x);
}

// pack two f32 -> one dword of 2 bf16 (RNE), single instruction
static __device__ __forceinline__ unsigned cvtpk(float lo, float hi) {
    unsigned r;
    asm("v_cvt_pk_bf16_f32 %0, %1, %2" : "=v"(r) : "v"(lo), "v"(hi));
    return r;
}

// half-wave swap: a' = {a_lo, b_lo}, b' = {a_hi, b_hi} (lanes 0-31 / 32-63)
static __device__ __forceinline__ void plswap(unsigned &a, unsigned &b) {
    asm("v_permlane32_swap_b32 %0, %1" : "+v"(a), "+v"(b));
}

static __device__ __forceinline__ bf16x8 as_bf16x8(u32x4 v) {
    return __builtin_bit_cast(bf16x8, v);
}

// async 16B/lane global -> LDS (DMA, no VGPR round-trip).
static __device__ __forceinline__ void gload16(const unsigned short* g, unsigned short* l) {
    __builtin_amdgcn_global_load_lds((const __attribute__((address_space(1))) void*)g,
                                     (__attribute__((address_space(3))) void*)l, 16, 0, 0);
}

// Stage 64 rows x 256 bf16 (global row stride 256 elems) -> LDS stride 264.
static __device__ __forceinline__ void stage_64x256(
    unsigned short* __restrict__ lds, const unsigned short* __restrict__ g, int tid)
{
    #pragma unroll
    for (int chunk = 0; chunk < 8; ++chunk) {
        const int row = chunk * 8 + (tid >> 5);
        const int col = (tid & 31) * 8;
        *(s16x8*)&lds[row * 264 + col] = *(const s16x8*)&g[row * 256 + col];
    }
}

// ---------------------------------------------------------------------------
// Kernel 0: weight prep (unchanged).
// ---------------------------------------------------------------------------
__global__ __launch_bounds__(256) void k_prep(
    const float* __restrict__ wqkv, const float* __restrict__ wproj,
    unsigned short* __restrict__ wqkv_t, unsigned short* __restrict__ wproj_bf)
{
    const int id = blockIdx.x;
    const int tid = threadIdx.x;
    if (id < 48) {
        __shared__ float T[64][65];
        const int jt = id % 12, ct = id / 12;
        #pragma unroll
        for (int p = 0; p < 16; ++p) {
            const int idx = tid + (p << 8);
            const int r = idx >> 6, cl = idx & 63;
            T[r][cl] = wqkv[(size_t)(ct * 64 + r) * 768 + jt * 64 + cl];
        }
        __syncthreads();
        #pragma unroll
        for (int p = 0; p < 16; ++p) {
            const int idx = tid + (p << 8);
            const int r = idx >> 6, cl = idx & 63;
            wqkv_t[(size_t)(jt * 64 + r) * 256 + ct * 64 + cl] = f2bf(T[cl][r]);
        }
    } else {
        const int base = (id - 48) * 2048 + tid * 8;
        s16x8 v;
        #pragma unroll
        for (int j = 0; j < 8; ++j) v[j] = (short)f2bf(wproj[base + j]);
        *(s16x8*)&wproj_bf[base] = v;
    }
}

// ---------------------------------------------------------------------------
// Kernel 1: LayerNorm + QKV GEMM via bf16 MFMA. (R6 version: LN computed
// once per block, three=0..2 looped internally.)
// ---------------------------------------------------------------------------
__global__ __launch_bounds__(256) void k_ln_qkv(
    const float* __restrict__ x,       // [B][C][N]
    const float* __restrict__ ln_g,
    const float* __restrict__ ln_b,
    const unsigned short* __restrict__ wqkv_t,  // [768][256] bf16
    unsigned short* __restrict__ q_bf,
    unsigned short* __restrict__ k_bf,
    unsigned short* __restrict__ v_bf)
{
    __shared__ unsigned short An[64 * 264];
    __shared__ unsigned short Wt[64 * 264];
    __shared__ float red1[4][64], red2[4][64];
    __shared__ float mu_s[64], rs_s[64];

    const int b     = blockIdx.x >> 6;
    const int n0    = (blockIdx.x & 63) << 6;
    const int tid   = threadIdx.x;
    const int li    = tid & 63;
    const int grp   = tid >> 6;
    const int w     = grp;
    const int lane  = li;
    const int q4    = lane >> 4;
    const int c     = lane & 15;

    const float* xb = x + ((size_t)b * NC) * NT + n0 + li;

    float xr[64];
    #pragma unroll
    for (int chunk = 0; chunk < 8; ++chunk)
        #pragma unroll
        for (int j = 0; j < 8; ++j)
            xr[chunk * 8 + j] = xb[(size_t)(chunk * 32 + grp * 8 + j) * NT];

    float s1 = 0.f, s2 = 0.f;
    #pragma unroll
    for (int i = 0; i < 64; ++i) { s1 += xr[i]; s2 += xr[i] * xr[i]; }
    red1[grp][li] = s1; red2[grp][li] = s2;
    __syncthreads();
    if (tid < 64) {
        const float t1 = red1[0][tid] + red1[1][tid] + red1[2][tid] + red1[3][tid];
        const float t2 = red2[0][tid] + red2[1][tid] + red2[2][tid] + red2[3][tid];
        const float mu  = t1 * (1.0f / NC);
        const float var = t2 * (1.0f / NC) - mu * mu;
        mu_s[tid] = mu;
        rs_s[tid] = rsqrtf(var + 1e-5f);
    }
    __syncthreads();
    const float mu = mu_s[li];
    const float rs = rs_s[li];

    #pragma unroll
    for (int chunk = 0; chunk < 8; ++chunk) {
        s16x8 pk;
        #pragma unroll
        for (int j = 0; j < 8; ++j) {
            const int ch = chunk * 32 + grp * 8 + j;
            const float vv = (xr[chunk * 8 + j] - mu) * rs * ln_g[ch] + ln_b[ch];
            pk[j] = (short)f2bf(vv);
        }
        *(s16x8*)&An[li * 264 + chunk * 32 + grp * 8] = pk;
    }
    __syncthreads();

    bf16x8 aT[8];
    #pragma unroll
    for (int kt = 0; kt < 8; ++kt)
        aT[kt] = *(const bf16x8*)&An[(16 * w + c) * 264 + kt * 32 + q4 * 8];

    for (int three = 0; three < 3; ++three) {
        for (int jt = 0; jt < 4; ++jt) {
            __syncthreads();
            stage_64x256(Wt, wqkv_t + (size_t)(three * 256 + jt * 64) * 256, tid);
            __syncthreads();

            f32x4 acc[4];
            #pragma unroll
            for (int nt = 0; nt < 4; ++nt)
                #pragma unroll
                for (int r = 0; r < 4; ++r) acc[nt][r] = 0.f;

            const int bh = b * NHEADS + jt;
            if (three < 2) {
                #pragma unroll
                for (int nt = 0; nt < 4; ++nt)
                    #pragma unroll
                    for (int kt = 0; kt < 8; ++kt) {
                        const bf16x8 bb = *(const bf16x8*)&Wt[(16 * nt + c) * 264 + kt * 32 + q4 * 8];
                        acc[nt] = __builtin_amdgcn_mfma_f32_16x16x32_bf16(aT[kt], bb, acc[nt], 0, 0, 0);
                    }
                unsigned short* dst = (three == 0 ? q_bf : k_bf) + ((size_t)bh * NT + n0) * DH;
                const float sc = (three == 0) ? QSCALE : 1.0f;
                #pragma unroll
                for (int nt = 0; nt < 4; ++nt)
                    #pragma unroll
                    for (int r = 0; r < 4; ++r)
                        dst[(size_t)(16 * w + 4 * q4 + r) * DH + 16 * nt + c] = f2bf(acc[nt][r] * sc);
            } else {
                bf16x8 aW[8];
                #pragma unroll
                for (int kt = 0; kt < 8; ++kt)
                    aW[kt] = *(const bf16x8*)&Wt[(16 * w + c) * 264 + kt * 32 + q4 * 8];
                #pragma unroll
                for (int nt = 0; nt < 4; ++nt)
                    #pragma unroll
                    for (int kt = 0; kt < 8; ++kt) {
                        const bf16x8 bb = *(const bf16x8*)&An[(16 * nt + c) * 264 + kt * 32 + q4 * 8];
                        acc[nt] = __builtin_amdgcn_mfma_f32_16x16x32_bf16(aW[kt], bb, acc[nt], 0, 0, 0);
                    }
                unsigned short* dst = v_bf + (size_t)bh * DH * NT;
                #pragma unroll
                for (int nt = 0; nt < 4; ++nt)
                    #pragma unroll
                    for (int r = 0; r < 4; ++r)
                        dst[(size_t)(16 * w + 4 * q4 + r) * NT + n0 + 16 * nt + c] = f2bf(acc[nt][r]);
            }
        }
    }
}

// ---------------------------------------------------------------------------
// Kernel 2: flash attention, 32x32x16 MFMA, in-register softmax.
// R8 change: 64 QUERIES PER WAVE (2 groups of 32). Every K/V fragment read
// from LDS feeds TWO MFMAs (one per query group) -> LDS ds_read_b128 per
// query halves (1.0 -> 0.5 reads/query), attacking the largest pipe term
// (LDS was ~48% of wall). Same verified sync skeleton as R2 (one fused
// vmcnt(0);s_barrier per iter, double-buffered K/V) — layout change only,
// no new race surface. Grid 256 blocks (16 bh x 16 qtiles of 256 q),
// 1 block/CU. All R6/R7 codegen experiments (SGB, Z-seed) reverted.
// ---------------------------------------------------------------------------
__global__ __launch_bounds__(256, 1) void k_attn(
    const unsigned short* __restrict__ qg,  // [bh][n][d], pre-scaled by QSCALE
    const unsigned short* __restrict__ kg,  // [bh][n][d]
    const unsigned short* __restrict__ vg,  // [bh][d][n]  (transposed)
    unsigned short* __restrict__ og)        // [bh][n][d] bf16, normalized
{
    __shared__ unsigned short Ks[2 * 8192];   // 2 x (128 keys x 64 d)
    __shared__ unsigned short Vt[2 * 8192];   // 2 x (64 d x 128 keys)
    __shared__ float l_s[4][64];

    // bijective XCD swizzle: 256 = 8 XCD x 32; each XCD gets 2 contiguous bh.
    const int bx   = ((blockIdx.x & 7) << 5) | (blockIdx.x >> 3);
    const int bh   = bx >> 4;                  // 0..15
    const int qt   = bx & 15;                  // 0..15
    const int n0   = qt << 8;                  // 256-query tile base
    const int tid  = threadIdx.x;
    const int w    = tid >> 6;                 // wave -> queries qb..qb+63
    const int lane = tid & 63;
    const int c5   = lane & 31;
    const int hi   = lane >> 5;
    const int qb   = n0 + (w << 6);
    const int swz  = c5 & 7;

    const unsigned short* kb = kg + (size_t)bh * NT * DH;
    const unsigned short* vb = vg + (size_t)bh * DH * NT;

    // ---- Q frags (2 groups of 32 queries): B-operand, lane(c5,hi) holds
    //      Q[query = qb + 32g + c5][d = 16ks + 8hi + e] ----
    bf16x8 aq[2][4];
    #pragma unroll
    for (int g = 0; g < 2; ++g) {
        const unsigned short* qrow =
            qg + ((size_t)bh * NT + qb + 32 * g + c5) * DH + hi * 8;
        #pragma unroll
        for (int ks = 0; ks < 4; ++ks)
            aq[g][ks] = *(const bf16x8*)(qrow + ks * 16);
    }

    // ---- staging lane geometry (per 1KB DMA instruction) ----
    // K tile rows = keys (128B each): 8 rows per 1KB group.
    const int rr  = lane >> 3;                 // row within 8-row group
    const int kcK = (lane & 7) ^ rr;           // swizzled 16B chunk (K)
    // V tile rows = d (256B each): 4 rows per 1KB group.
    const int rd  = lane >> 4;                 // d-row within 4-row group
    const int ckV = lane & 15;                 // 16B chunk within 256B row

    #define ISSUE_TILE(it_, bi_)                                               \
        {                                                                      \
            const unsigned short* ktp = kb + (size_t)(it_) * 128 * DH;         \
            const unsigned short* vtp = vb + (size_t)(it_) * 128;              \
            _Pragma("unroll")                                                  \
            for (int t = 0; t < 4; ++t) {                                      \
                const int grp_ = w * 4 + t;                                    \
                gload16(ktp + (size_t)(grp_ * 8 + rr) * DH + kcK * 8,          \
                        &Ks[(bi_) * 8192 + grp_ * 512 + lane * 8]);            \
                const int kcV_ = ckV ^ ((4 * grp_ + rd) & 7);                  \
                gload16(vtp + (size_t)(4 * grp_ + rd) * NT + kcV_ * 8,         \
                        &Vt[(bi_) * 8192 + grp_ * 512 + lane * 8]);            \
            }                                                                  \
        }

    // ---- QK for one 32-key sub-block, BOTH query groups share kf ----
    #define QK_SB2(sv0, sv1, sb)                                               \
        {                                                                      \
            _Pragma("unroll")                                                  \
            for (int ks = 0; ks < 4; ++ks) {                                   \
                const bf16x8 kf = *(const bf16x8*)                             \
                    &Kb[((sb) * 32 + c5) * 64 + (((2 * ks + hi) ^ swz) << 3)]; \
                sv0 = __builtin_amdgcn_mfma_f32_32x32x16_bf16(kf, aq[0][ks], sv0, 0, 0, 0); \
                sv1 = __builtin_amdgcn_mfma_f32_32x32x16_bf16(kf, aq[1][ks], sv1, 0, 0, 0); \
            }                                                                  \
        }

    #define EXP_SB(sv, g)                                                      \
        {                                                                      \
            _Pragma("unroll")                                                  \
            for (int r = 0; r < 16; r += 4) {                                  \
                sv[r]   = fast_exp2(sv[r]);   lsg[g][0] += sv[r];              \
                sv[r+1] = fast_exp2(sv[r+1]); lsg[g][1] += sv[r+1];            \
                sv[r+2] = fast_exp2(sv[r+2]); lsg[g][2] += sv[r+2];            \
                sv[r+3] = fast_exp2(sv[r+3]); lsg[g][3] += sv[r+3];            \
            }                                                                  \
        }

    #define PACK_SB(sv, pa0, pa1)                                              \
        {                                                                      \
            unsigned x0 = cvtpk(sv[0], sv[1]),  x1 = cvtpk(sv[4], sv[5]);      \
            plswap(x0, x1);                                                    \
            unsigned x2 = cvtpk(sv[2], sv[3]),  x3 = cvtpk(sv[6], sv[7]);      \
            plswap(x2, x3);                                                    \
            pa0 = (u32x4){x0, x2, x1, x3};                                     \
            unsigned y0 = cvtpk(sv[8], sv[9]),  y1 = cvtpk(sv[12], sv[13]);    \
            plswap(y0, y1);                                                    \
            unsigned y2 = cvtpk(sv[10], sv[11]), y3 = cvtpk(sv[14], sv[15]);   \
            plswap(y2, y3);                                                    \
            pa1 = (u32x4){y0, y2, y1, y3};                                     \
        }

    // ---- PV for one sub-block: V frags shared by BOTH query groups ----
    #define PV_SB2(p00, p01, p10, p11, sb)                                     \
        {                                                                      \
            _Pragma("unroll")                                                  \
            for (int dt = 0; dt < 2; ++dt) {                                   \
                const int rv = (dt * 32 + c5) * 128;                           \
                const bf16x8 vA = *(const bf16x8*)                             \
                    &Vb[rv + (((4 * (sb) + hi) ^ swz) << 3)];                  \
                oac[0][dt] = __builtin_amdgcn_mfma_f32_32x32x16_bf16(          \
                    as_bf16x8(p00), vA, oac[0][dt], 0, 0, 0);                  \
                oac[1][dt] = __builtin_amdgcn_mfma_f32_32x32x16_bf16(          \
                    as_bf16x8(p10), vA, oac[1][dt], 0, 0, 0);                  \
                const bf16x8 vB = *(const bf16x8*)                             \
                    &Vb[rv + (((4 * (sb) + 2 + hi) ^ swz) << 3)];              \
                oac[0][dt] = __builtin_amdgcn_mfma_f32_32x32x16_bf16(          \
                    as_bf16x8(p01), vB, oac[0][dt], 0, 0, 0);                  \
                oac[1][dt] = __builtin_amdgcn_mfma_f32_32x32x16_bf16(          \
                    as_bf16x8(p11), vB, oac[1][dt], 0, 0, 0);                  \
            }                                                                  \
        }

    ISSUE_TILE(0, 0)

    f32x16 oac[2][2];                          // [group][dt]
    #pragma unroll
    for (int g = 0; g < 2; ++g)
        #pragma unroll
        for (int dt = 0; dt < 2; ++dt)
            #pragma unroll
            for (int r = 0; r < 16; ++r) oac[g][dt][r] = 0.f;
    float lsg[2][4] = {};                      // [group][chain]

    for (int it = 0; it < 32; ++it) {
        const int cur = it & 1;
        asm volatile("s_waitcnt vmcnt(0)\n\ts_barrier" ::: "memory");
        if (it < 31) ISSUE_TILE(it + 1, cur ^ 1)

        const unsigned short* Kb = &Ks[cur * 8192];
        const unsigned short* Vb = &Vt[cur * 8192];

        // two 64-key halves per 128-key tile; per half: 2 sub-blocks x 2 groups
        #pragma unroll
        for (int hf = 0; hf < 2; ++hf) {
            const int sb0 = 2 * hf, sb1 = 2 * hf + 1;

            f32x16 s00, s01, s10, s11;         // [sb(0/1) of pair][group]
            #pragma unroll
            for (int r = 0; r < 16; ++r) { s00[r]=0.f; s01[r]=0.f; s10[r]=0.f; s11[r]=0.f; }

            __builtin_amdgcn_s_setprio(1);
            QK_SB2(s00, s01, sb0)
            QK_SB2(s10, s11, sb1)
            __builtin_amdgcn_s_setprio(0);

            EXP_SB(s00, 0)
            EXP_SB(s01, 1)
            EXP_SB(s10, 0)
            EXP_SB(s11, 1)

            u32x4 p00a, p00b, p01a, p01b, p10a, p10b, p11a, p11b;
            PACK_SB(s00, p00a, p00b)           // sb0, group0
            PACK_SB(s01, p01a, p01b)           // sb0, group1
            PACK_SB(s10, p10a, p10b)           // sb1, group0
            PACK_SB(s11, p11a, p11b)           // sb1, group1

            __builtin_amdgcn_s_setprio(1);
            PV_SB2(p00a, p00b, p01a, p01b, sb0)
            PV_SB2(p10a, p10b, p11a, p11b, sb1)
            __builtin_amdgcn_s_setprio(0);
        }
    }
    #undef ISSUE_TILE
    #undef QK_SB2
    #undef EXP_SB
    #undef PACK_SB
    #undef PV_SB2

    // ---- per-query l: group g query c5 -> lane c5 both halves ----
    #pragma unroll
    for (int g = 0; g < 2; ++g) {
        const float lsum = (lsg[g][0] + lsg[g][1]) + (lsg[g][2] + lsg[g][3]);
        const float t = lsum + __shfl_xor(lsum, 32);
        if (lane < 32) l_s[w][32 * g + c5] = t;
    }
    __syncthreads();

    // ---- normalize + write bf16 O: row r -> query (r&3)+8*(r>>2)+4*hi ----
    unsigned short* ob = og + ((size_t)bh * NT + qb) * DH;
    #pragma unroll
    for (int g = 0; g < 2; ++g)
        #pragma unroll
        for (int r = 0; r < 16; ++r) {
            const int qrow = (r & 3) + 8 * (r >> 2) + 4 * hi;
            const float rn = 1.0f / l_s[w][32 * g + qrow];
            ob[(size_t)(32 * g + qrow) * DH + c5]      = f2bf(oac[g][0][r] * rn);
            ob[(size_t)(32 * g + qrow) * DH + 32 + c5] = f2bf(oac[g][1][r] * rn);
        }
}

// ---------------------------------------------------------------------------
// Kernel 3: output projection via bf16 MFMA. (unchanged)
// ---------------------------------------------------------------------------
__global__ __launch_bounds__(256) void k_proj(
    const unsigned short* __restrict__ o_bf,     // [bh][n][64] bf16 normalized
    const unsigned short* __restrict__ wproj_bf, // [256][256] bf16
    const float* __restrict__ b_proj,
    float* __restrict__ out)                     // [B][C][N]
{
    __shared__ unsigned short Os[64 * 264];
    __shared__ unsigned short Ws[64 * 264];

    const int b   = blockIdx.x >> 6;
    const int n0  = (blockIdx.x & 63) << 6;
    const int yh  = blockIdx.y;                  // 0..1 -> cg half
    const int tid = threadIdx.x;
    const int w   = tid >> 6;
    const int lane = tid & 63;
    const int q4  = lane >> 4;
    const int c   = lane & 15;

    // ---- stage O tile: [token][c = hd*64 + d] bf16, direct 16B copies ----
    #pragma unroll
    for (int chunk = 0; chunk < 8; ++chunk) {
        const int row = chunk * 8 + (tid >> 5);
        const int col = (tid & 31) * 8;
        const int hd  = col >> 6;
        const int c64 = col & 63;
        const unsigned short* src =
            &o_bf[((size_t)(b * NHEADS + hd) * NT + n0 + row) * DH + c64];
        *(s16x8*)&Os[row * 264 + col] = *(const s16x8*)src;
    }

    for (int ct = 0; ct < 2; ++ct) {
        const int cg0 = (yh * 2 + ct) * 64;
        if (ct) __syncthreads();                 // Ws reuse guard
        stage_64x256(Ws, wproj_bf + (size_t)cg0 * NC, tid);
        __syncthreads();                         // Ws (and on ct==0, Os) visible

        bf16x8 a[8];
        #pragma unroll
        for (int kt = 0; kt < 8; ++kt)
            a[kt] = *(const bf16x8*)&Ws[(16 * w + c) * 264 + kt * 32 + q4 * 8];

        f32x4 acc[4];
        #pragma unroll
        for (int nt = 0; nt < 4; ++nt)
            #pragma unroll
            for (int r = 0; r < 4; ++r) acc[nt][r] = 0.f;

        #pragma unroll
        for (int nt = 0; nt < 4; ++nt)
            #pragma unroll
            for (int kt = 0; kt < 8; ++kt) {
                const bf16x8 bb = *(const bf16x8*)&Os[(16 * nt + c) * 264 + kt * 32 + q4 * 8];
                acc[nt] = __builtin_amdgcn_mfma_f32_16x16x32_bf16(a[kt], bb, acc[nt], 0, 0, 0);
            }

        #pragma unroll
        for (int nt = 0; nt < 4; ++nt)
            #pragma unroll
            for (int r = 0; r < 4; ++r) {
                const int cg = cg0 + 16 * w + 4 * q4 + r;
                out[((size_t)b * NC + cg) * NT + n0 + 16 * nt + c] = acc[nt][r] + b_proj[cg];
            }
    }
}

// ---------------------------------------------------------------------------
extern "C" void kernel_launch(void* const* d_in, const int* in_sizes, int n_in,
                              void* d_out, int out_size, void* d_ws, size_t ws_size,
                              hipStream_t stream)
{
    const float* x      = (const float*)d_in[0];
    const float* ln_g   = (const float*)d_in[1];
    const float* ln_b   = (const float*)d_in[2];
    const float* w_qkv  = (const float*)d_in[3];
    const float* w_proj = (const float*)d_in[4];
    const float* b_proj = (const float*)d_in[5];
    float* out = (float*)d_out;

    const size_t TEN = (size_t)NB * NHEADS * NT * DH;   // 4,194,304 elements

    unsigned short* ws16 = (unsigned short*)d_ws;
    unsigned short* q_bf    = ws16;
    unsigned short* k_bf    = ws16 + TEN;
    unsigned short* v_bf    = ws16 + 2 * TEN;
    unsigned short* o_bf    = ws16 + 3 * TEN;
    unsigned short* wqkv_t  = ws16 + 4 * TEN;            // [768][256]
    unsigned short* wproj_b = wqkv_t + 768 * 256;        // [256][256]

    k_prep<<<80, 256, 0, stream>>>(w_qkv, w_proj, wqkv_t, wproj_b);
    k_ln_qkv<<<NB * 64, 256, 0, stream>>>(x, ln_g, ln_b, wqkv_t, q_bf, k_bf, v_bf);
    k_attn<<<256, 256, 0, stream>>>(q_bf, k_bf, v_bf, o_bf);
    k_proj<<<dim3(NB * 64, 2), 256, 0, stream>>>(o_bf, wproj_b, b_proj, out);
}

// Round 9
// 185.345 us; speedup vs baseline: 1.0850x; 1.0850x over previous
//
#include <hip/hip_runtime.h>
#include <math.h>

#define NB 4
#define NC 256
#define NHEADS 4
#define DH 64
#define NT 4096            // 64*64 tokens per batch
// q pre-scale with log2(e) folded in: exp(s/8) == exp2(s * QSCALE)
#define QSCALE (0.125f * 1.44269504088896f)

typedef __bf16  bf16x8 __attribute__((ext_vector_type(8)));
typedef float   f32x4  __attribute__((ext_vector_type(4)));
typedef float   f32x16 __attribute__((ext_vector_type(16)));
typedef short   s16x8  __attribute__((ext_vector_type(8)));
typedef unsigned int u32x4 __attribute__((ext_vector_type(4)));

static __device__ __forceinline__ unsigned short f2bf(float f) {
    unsigned u = __float_as_uint(f);
    u = (u + 0x7fffu + ((u >> 16) & 1u)) >> 16;   // round-to-nearest-even
    return (unsigned short)u;
}

static __device__ __forceinline__ float fast_exp2(float x) {
    return __builtin_amdgcn_exp2f(x);
}

// pack two f32 -> one dword of 2 bf16 (RNE), single instruction
static __device__ __forceinline__ unsigned cvtpk(float lo, float hi) {
    unsigned r;
    asm("v_cvt_pk_bf16_f32 %0, %1, %2" : "=v"(r) : "v"(lo), "v"(hi));
    return r;
}

// half-wave swap: a' = {a_lo, b_lo}, b' = {a_hi, b_hi} (lanes 0-31 / 32-63)
static __device__ __forceinline__ void plswap(unsigned &a, unsigned &b) {
    asm("v_permlane32_swap_b32 %0, %1" : "+v"(a), "+v"(b));
}

static __device__ __forceinline__ bf16x8 as_bf16x8(u32x4 v) {
    return __builtin_bit_cast(bf16x8, v);
}

// async 16B/lane global -> LDS (DMA, no VGPR round-trip).
static __device__ __forceinline__ void gload16(const unsigned short* g, unsigned short* l) {
    __builtin_amdgcn_global_load_lds((const __attribute__((address_space(1))) void*)g,
                                     (__attribute__((address_space(3))) void*)l, 16, 0, 0);
}

// Stage 64 rows x 256 bf16 (global row stride 256 elems) -> LDS stride 264.
static __device__ __forceinline__ void stage_64x256(
    unsigned short* __restrict__ lds, const unsigned short* __restrict__ g, int tid)
{
    #pragma unroll
    for (int chunk = 0; chunk < 8; ++chunk) {
        const int row = chunk * 8 + (tid >> 5);
        const int col = (tid & 31) * 8;
        *(s16x8*)&lds[row * 264 + col] = *(const s16x8*)&g[row * 256 + col];
    }
}

// ---------------------------------------------------------------------------
// Kernel 0: weight prep (unchanged).
// ---------------------------------------------------------------------------
__global__ __launch_bounds__(256) void k_prep(
    const float* __restrict__ wqkv, const float* __restrict__ wproj,
    unsigned short* __restrict__ wqkv_t, unsigned short* __restrict__ wproj_bf)
{
    const int id = blockIdx.x;
    const int tid = threadIdx.x;
    if (id < 48) {
        __shared__ float T[64][65];
        const int jt = id % 12, ct = id / 12;
        #pragma unroll
        for (int p = 0; p < 16; ++p) {
            const int idx = tid + (p << 8);
            const int r = idx >> 6, cl = idx & 63;
            T[r][cl] = wqkv[(size_t)(ct * 64 + r) * 768 + jt * 64 + cl];
        }
        __syncthreads();
        #pragma unroll
        for (int p = 0; p < 16; ++p) {
            const int idx = tid + (p << 8);
            const int r = idx >> 6, cl = idx & 63;
            wqkv_t[(size_t)(jt * 64 + r) * 256 + ct * 64 + cl] = f2bf(T[cl][r]);
        }
    } else {
        const int base = (id - 48) * 2048 + tid * 8;
        s16x8 v;
        #pragma unroll
        for (int j = 0; j < 8; ++j) v[j] = (short)f2bf(wproj[base + j]);
        *(s16x8*)&wproj_bf[base] = v;
    }
}

// ---------------------------------------------------------------------------
// Kernel 1: LayerNorm + QKV GEMM via bf16 MFMA.
// R9 change: Wt staging via DMA (global_load_lds) with DOUBLE BUFFERING and
// the k_attn-proven one-fused-vmcnt(0)+barrier-per-tile skeleton. Weight
// fetch of tile i+1 overlaps MFMA of tile i; tile-0 DMA issued at kernel top
// so it overlaps the x-load/LN phase. Linear LDS dest (DMA requirement) with
// XOR-pre-swizzled global source + matching XOR on fragment reads
// (lanes (c,q4) -> 32 distinct 16B chunks, conflict-free).
// grid=256 -> exactly 1 block/CU either way (no occupancy change).
// ---------------------------------------------------------------------------
__global__ __launch_bounds__(256) void k_ln_qkv(
    const float* __restrict__ x,       // [B][C][N]
    const float* __restrict__ ln_g,
    const float* __restrict__ ln_b,
    const unsigned short* __restrict__ wqkv_t,  // [768][256] bf16
    unsigned short* __restrict__ q_bf,
    unsigned short* __restrict__ k_bf,
    unsigned short* __restrict__ v_bf)
{
    __shared__ unsigned short An[64 * 264];
    __shared__ unsigned short Wt[2][64 * 256];   // linear (DMA dest)
    __shared__ float red1[4][64], red2[4][64];
    __shared__ float mu_s[64], rs_s[64];

    const int b     = blockIdx.x >> 6;
    const int n0    = (blockIdx.x & 63) << 6;
    const int tid   = threadIdx.x;
    const int li    = tid & 63;
    const int grp   = tid >> 6;
    const int w     = grp;
    const int lane  = li;
    const int q4    = lane >> 4;
    const int c     = lane & 15;

    // ---- weight DMA lane geometry: 1KB group = 2 rows of 512B ----
    const int wrow2  = lane >> 5;              // row within 2-row group
    const int wchunk = lane & 31;              // 16B chunk within 512B row

    #define ISSUE_W(idx_, buf_)                                                \
        {                                                                      \
            const unsigned short* wsrc = wqkv_t + (size_t)(idx_) * 64 * 256;   \
            _Pragma("unroll")                                                  \
            for (int t = 0; t < 8; ++t) {                                      \
                const int g_ = w * 8 + t;                                      \
                const int r_ = 2 * g_ + wrow2;                                 \
                gload16(wsrc + r_ * 256 + ((wchunk ^ (r_ & 7)) << 3),          \
                        &Wt[buf_][g_ * 512 + lane * 8]);                       \
            }                                                                  \
        }

    ISSUE_W(0, 0)                              // overlaps x-load + LN below

    const float* xb = x + ((size_t)b * NC) * NT + n0 + li;

    float xr[64];
    #pragma unroll
    for (int chunk = 0; chunk < 8; ++chunk)
        #pragma unroll
        for (int j = 0; j < 8; ++j)
            xr[chunk * 8 + j] = xb[(size_t)(chunk * 32 + grp * 8 + j) * NT];

    float s1 = 0.f, s2 = 0.f;
    #pragma unroll
    for (int i = 0; i < 64; ++i) { s1 += xr[i]; s2 += xr[i] * xr[i]; }
    red1[grp][li] = s1; red2[grp][li] = s2;
    __syncthreads();
    if (tid < 64) {
        const float t1 = red1[0][tid] + red1[1][tid] + red1[2][tid] + red1[3][tid];
        const float t2 = red2[0][tid] + red2[1][tid] + red2[2][tid] + red2[3][tid];
        const float mu  = t1 * (1.0f / NC);
        const float var = t2 * (1.0f / NC) - mu * mu;
        mu_s[tid] = mu;
        rs_s[tid] = rsqrtf(var + 1e-5f);
    }
    __syncthreads();
    const float mu = mu_s[li];
    const float rs = rs_s[li];

    #pragma unroll
    for (int chunk = 0; chunk < 8; ++chunk) {
        s16x8 pk;
        #pragma unroll
        for (int j = 0; j < 8; ++j) {
            const int ch = chunk * 32 + grp * 8 + j;
            const float vv = (xr[chunk * 8 + j] - mu) * rs * ln_g[ch] + ln_b[ch];
            pk[j] = (short)f2bf(vv);
        }
        *(s16x8*)&An[li * 264 + chunk * 32 + grp * 8] = pk;
    }
    __syncthreads();

    bf16x8 aT[8];
    #pragma unroll
    for (int kt = 0; kt < 8; ++kt)
        aT[kt] = *(const bf16x8*)&An[(16 * w + c) * 264 + kt * 32 + q4 * 8];

    for (int idx = 0; idx < 12; ++idx) {       // idx = three*4 + jt
        const int buf = idx & 1;
        asm volatile("s_waitcnt vmcnt(0)\n\ts_barrier" ::: "memory");
        if (idx < 11) ISSUE_W(idx + 1, buf ^ 1)

        const int three = idx >> 2;
        const int jt    = idx & 3;

        f32x4 acc[4];
        #pragma unroll
        for (int nt = 0; nt < 4; ++nt)
            #pragma unroll
            for (int r = 0; r < 4; ++r) acc[nt][r] = 0.f;

        const int bh = b * NHEADS + jt;
        if (three < 2) {
            #pragma unroll
            for (int nt = 0; nt < 4; ++nt) {
                const int row = 16 * nt + c;
                #pragma unroll
                for (int kt = 0; kt < 8; ++kt) {
                    const bf16x8 bb = *(const bf16x8*)
                        &Wt[buf][row * 256 + (((4 * kt + q4) ^ (row & 7)) << 3)];
                    acc[nt] = __builtin_amdgcn_mfma_f32_16x16x32_bf16(aT[kt], bb, acc[nt], 0, 0, 0);
                }
            }
            unsigned short* dst = (three == 0 ? q_bf : k_bf) + ((size_t)bh * NT + n0) * DH;
            const float sc = (three == 0) ? QSCALE : 1.0f;
            #pragma unroll
            for (int nt = 0; nt < 4; ++nt)
                #pragma unroll
                for (int r = 0; r < 4; ++r)
                    dst[(size_t)(16 * w + 4 * q4 + r) * DH + 16 * nt + c] = f2bf(acc[nt][r] * sc);
        } else {
            bf16x8 aW[8];
            const int wrow = 16 * w + c;
            #pragma unroll
            for (int kt = 0; kt < 8; ++kt)
                aW[kt] = *(const bf16x8*)
                    &Wt[buf][wrow * 256 + (((4 * kt + q4) ^ (wrow & 7)) << 3)];
            #pragma unroll
            for (int nt = 0; nt < 4; ++nt)
                #pragma unroll
                for (int kt = 0; kt < 8; ++kt) {
                    const bf16x8 bb = *(const bf16x8*)&An[(16 * nt + c) * 264 + kt * 32 + q4 * 8];
                    acc[nt] = __builtin_amdgcn_mfma_f32_16x16x32_bf16(aW[kt], bb, acc[nt], 0, 0, 0);
                }
            unsigned short* dst = v_bf + (size_t)bh * DH * NT;
            #pragma unroll
            for (int nt = 0; nt < 4; ++nt)
                #pragma unroll
                for (int r = 0; r < 4; ++r)
                    dst[(size_t)(16 * w + 4 * q4 + r) * NT + n0 + 16 * nt + c] = f2bf(acc[nt][r]);
        }
    }
    #undef ISSUE_W
}

// ---------------------------------------------------------------------------
// Kernel 2: NO-split-K flash attention, 32x32x16 MFMA, in-register softmax.
// R2 version verbatim — best measured (85.6 us, VGPR 88). Pair-staggered
// epilogue, double-buffered 128-key tiles, one fused vmcnt(0)+barrier/iter.
// k_attn is CLOSED: schedule (R3/R6/R7), occupancy (R1), and LDS-traffic
// (R8) levers all proven non-binding; floor is per-wave chain latency at
// >=2 waves/SIMD.
// ---------------------------------------------------------------------------
__global__ __launch_bounds__(256, 2) void k_attn(
    const unsigned short* __restrict__ qg,  // [bh][n][d], pre-scaled by QSCALE
    const unsigned short* __restrict__ kg,  // [bh][n][d]
    const unsigned short* __restrict__ vg,  // [bh][d][n]  (transposed)
    unsigned short* __restrict__ og)        // [bh][n][d] bf16, normalized
{
    __shared__ unsigned short Ks[2 * 8192];   // 2 x (128 keys x 64 d)
    __shared__ unsigned short Vt[2 * 8192];   // 2 x (64 d x 128 keys)
    __shared__ float l_s[4][32];

    // bijective XCD swizzle: 512 = 8 XCD x 64; each XCD gets 2 contiguous bh.
    const int bx   = ((blockIdx.x & 7) << 6) | (blockIdx.x >> 3);
    const int bh   = bx >> 5;                  // 0..15
    const int qt   = bx & 31;                  // 0..31
    const int n0   = qt << 7;                  // 128-query tile base
    const int tid  = threadIdx.x;
    const int w    = tid >> 6;                 // wave -> queries qb..qb+31
    const int lane = tid & 63;
    const int c5   = lane & 31;
    const int hi   = lane >> 5;
    const int qb   = n0 + (w << 5);
    const int swz  = c5 & 7;

    const unsigned short* kb = kg + (size_t)bh * NT * DH;
    const unsigned short* vb = vg + (size_t)bh * DH * NT;

    // ---- Q frags direct from global: B-operand, lane(c5,hi) holds
    //      Q[query=qb+c5][d = 16ks + 8hi + e] ----
    bf16x8 aq[4];
    {
        const unsigned short* qrow = qg + ((size_t)bh * NT + qb + c5) * DH + hi * 8;
        #pragma unroll
        for (int ks = 0; ks < 4; ++ks)
            aq[ks] = *(const bf16x8*)(qrow + ks * 16);
    }

    // ---- staging lane geometry (per 1KB DMA instruction) ----
    // K tile rows = keys (128B each): 8 rows per 1KB group.
    const int rr  = lane >> 3;                 // row within 8-row group
    const int kcK = (lane & 7) ^ rr;           // swizzled 16B chunk (K)
    // V tile rows = d (256B each): 4 rows per 1KB group.
    const int rd  = lane >> 4;                 // d-row within 4-row group
    const int ckV = lane & 15;                 // 16B chunk within 256B row

    #define ISSUE_TILE(it_, bi_)                                               \
        {                                                                      \
            const unsigned short* ktp = kb + (size_t)(it_) * 128 * DH;         \
            const unsigned short* vtp = vb + (size_t)(it_) * 128;              \
            _Pragma("unroll")                                                  \
            for (int t = 0; t < 4; ++t) {                                      \
                const int grp_ = w * 4 + t;                                    \
                gload16(ktp + (size_t)(grp_ * 8 + rr) * DH + kcK * 8,          \
                        &Ks[(bi_) * 8192 + grp_ * 512 + lane * 8]);            \
                const int kcV_ = ckV ^ ((4 * grp_ + rd) & 7);                  \
                gload16(vtp + (size_t)(4 * grp_ + rd) * NT + kcV_ * 8,         \
                        &Vt[(bi_) * 8192 + grp_ * 512 + lane * 8]);            \
            }                                                                  \
        }

    ISSUE_TILE(0, 0)

    f32x16 oac[2];
    #pragma unroll
    for (int dt = 0; dt < 2; ++dt)
        #pragma unroll
        for (int r = 0; r < 16; ++r) oac[dt][r] = 0.f;
    float ls0 = 0.f, ls1 = 0.f, ls2 = 0.f, ls3 = 0.f;   // 4 partial l chains

    for (int it = 0; it < 32; ++it) {
        const int cur = it & 1;
        asm volatile("s_waitcnt vmcnt(0)\n\ts_barrier" ::: "memory");
        if (it < 31) ISSUE_TILE(it + 1, cur ^ 1)

        const unsigned short* Kb = &Ks[cur * 8192];
        const unsigned short* Vb = &Vt[cur * 8192];

        // four 32-key sub-blocks, processed as two batched pairs
        #pragma unroll
        for (int hf = 0; hf < 2; ++hf) {
            const int sb0 = 2 * hf, sb1 = 2 * hf + 1;

            // ---- S^T = K Q^T over d=64, two independent chains ----
            f32x16 s0, s1;
            #pragma unroll
            for (int r = 0; r < 16; ++r) { s0[r] = 0.f; s1[r] = 0.f; }
            __builtin_amdgcn_s_setprio(1);
            #pragma unroll
            for (int ks = 0; ks < 4; ++ks) {
                const bf16x8 kf0 = *(const bf16x8*)
                    &Kb[(sb0 * 32 + c5) * 64 + (((2 * ks + hi) ^ swz) << 3)];
                s0 = __builtin_amdgcn_mfma_f32_32x32x16_bf16(kf0, aq[ks], s0, 0, 0, 0);
            }
            #pragma unroll
            for (int ks = 0; ks < 4; ++ks) {
                const bf16x8 kf1 = *(const bf16x8*)
                    &Kb[(sb1 * 32 + c5) * 64 + (((2 * ks + hi) ^ swz) << 3)];
                s1 = __builtin_amdgcn_mfma_f32_32x32x16_bf16(kf1, aq[ks], s1, 0, 0, 0);
            }
            __builtin_amdgcn_s_setprio(0);

            // ---- exp (max-free) + l partials ----
            #pragma unroll
            for (int r = 0; r < 16; r += 4) {
                s0[r]   = fast_exp2(s0[r]);   ls0 += s0[r];
                s0[r+1] = fast_exp2(s0[r+1]); ls1 += s0[r+1];
                s0[r+2] = fast_exp2(s0[r+2]); ls2 += s0[r+2];
                s0[r+3] = fast_exp2(s0[r+3]); ls3 += s0[r+3];
            }
            #pragma unroll
            for (int r = 0; r < 16; r += 4) {
                s1[r]   = fast_exp2(s1[r]);   ls0 += s1[r];
                s1[r+1] = fast_exp2(s1[r+1]); ls1 += s1[r+1];
                s1[r+2] = fast_exp2(s1[r+2]); ls2 += s1[r+2];
                s1[r+3] = fast_exp2(s1[r+3]); ls3 += s1[r+3];
            }

            // ---- in-register P -> PV A-frags (cvt_pk + permlane32_swap) ----
            unsigned A0 = cvtpk(s0[0],  s0[1]),  A1 = cvtpk(s0[4],  s0[5]);
            plswap(A0, A1);
            unsigned A2 = cvtpk(s0[2],  s0[3]),  A3 = cvtpk(s0[6],  s0[7]);
            plswap(A2, A3);
            const u32x4 paA0 = (u32x4){A0, A2, A1, A3};     // sb0 keys 0..15
            unsigned B0 = cvtpk(s0[8],  s0[9]),  B1 = cvtpk(s0[12], s0[13]);
            plswap(B0, B1);
            unsigned B2 = cvtpk(s0[10], s0[11]), B3 = cvtpk(s0[14], s0[15]);
            plswap(B2, B3);
            const u32x4 paB0 = (u32x4){B0, B2, B1, B3};     // sb0 keys 16..31
            unsigned C0 = cvtpk(s1[0],  s1[1]),  C1 = cvtpk(s1[4],  s1[5]);
            plswap(C0, C1);
            unsigned C2 = cvtpk(s1[2],  s1[3]),  C3 = cvtpk(s1[6],  s1[7]);
            plswap(C2, C3);
            const u32x4 paA1 = (u32x4){C0, C2, C1, C3};     // sb1 keys 0..15
            unsigned D0 = cvtpk(s1[8],  s1[9]),  D1 = cvtpk(s1[12], s1[13]);
            plswap(D0, D1);
            unsigned D2 = cvtpk(s1[10], s1[11]), D3 = cvtpk(s1[14], s1[15]);
            plswap(D2, D3);
            const u32x4 paB1 = (u32x4){D0, D2, D1, D3};     // sb1 keys 16..31

            // ---- PV: B = V^T frags; V chunk j = 4*sb + 2*s + hi ----
            __builtin_amdgcn_s_setprio(1);
            #pragma unroll
            for (int dt = 0; dt < 2; ++dt) {
                const int rv = (dt * 32 + c5) * 128;
                const bf16x8 vA0 = *(const bf16x8*)&Vb[rv + (((4*sb0 + hi) ^ swz) << 3)];
                oac[dt] = __builtin_amdgcn_mfma_f32_32x32x16_bf16(
                    as_bf16x8(paA0), vA0, oac[dt], 0, 0, 0);
                const bf16x8 vB0 = *(const bf16x8*)&Vb[rv + (((4*sb0 + 2 + hi) ^ swz) << 3)];
                oac[dt] = __builtin_amdgcn_mfma_f32_32x32x16_bf16(
                    as_bf16x8(paB0), vB0, oac[dt], 0, 0, 0);
                const bf16x8 vA1 = *(const bf16x8*)&Vb[rv + (((4*sb1 + hi) ^ swz) << 3)];
                oac[dt] = __builtin_amdgcn_mfma_f32_32x32x16_bf16(
                    as_bf16x8(paA1), vA1, oac[dt], 0, 0, 0);
                const bf16x8 vB1 = *(const bf16x8*)&Vb[rv + (((4*sb1 + 2 + hi) ^ swz) << 3)];
                oac[dt] = __builtin_amdgcn_mfma_f32_32x32x16_bf16(
                    as_bf16x8(paB1), vB1, oac[dt], 0, 0, 0);
            }
            __builtin_amdgcn_s_setprio(0);
        }
    }
    #undef ISSUE_TILE

    // ---- per-query l: query c5 owned by this wave; redistribute via LDS ----
    const float lsum = (ls0 + ls1) + (ls2 + ls3);
    const float t = lsum + __shfl_xor(lsum, 32);
    if (lane < 32) l_s[w][c5] = t;
    __syncthreads();

    // ---- normalize + write bf16 O: row r -> query (r&3)+8*(r>>2)+4*hi ----
    unsigned short* ob = og + ((size_t)bh * NT + qb) * DH;
    #pragma unroll
    for (int r = 0; r < 16; ++r) {
        const int qrow = (r & 3) + 8 * (r >> 2) + 4 * hi;
        const float rn = 1.0f / l_s[w][qrow];
        ob[(size_t)qrow * DH + c5]      = f2bf(oac[0][r] * rn);
        ob[(size_t)qrow * DH + 32 + c5] = f2bf(oac[1][r] * rn);
    }
}

// ---------------------------------------------------------------------------
// Kernel 3: output projection via bf16 MFMA. (unchanged)
// ---------------------------------------------------------------------------
__global__ __launch_bounds__(256) void k_proj(
    const unsigned short* __restrict__ o_bf,     // [bh][n][64] bf16 normalized
    const unsigned short* __restrict__ wproj_bf, // [256][256] bf16
    const float* __restrict__ b_proj,
    float* __restrict__ out)                     // [B][C][N]
{
    __shared__ unsigned short Os[64 * 264];
    __shared__ unsigned short Ws[64 * 264];

    const int b   = blockIdx.x >> 6;
    const int n0  = (blockIdx.x & 63) << 6;
    const int yh  = blockIdx.y;                  // 0..1 -> cg half
    const int tid = threadIdx.x;
    const int w   = tid >> 6;
    const int lane = tid & 63;
    const int q4  = lane >> 4;
    const int c   = lane & 15;

    // ---- stage O tile: [token][c = hd*64 + d] bf16, direct 16B copies ----
    #pragma unroll
    for (int chunk = 0; chunk < 8; ++chunk) {
        const int row = chunk * 8 + (tid >> 5);
        const int col = (tid & 31) * 8;
        const int hd  = col >> 6;
        const int c64 = col & 63;
        const unsigned short* src =
            &o_bf[((size_t)(b * NHEADS + hd) * NT + n0 + row) * DH + c64];
        *(s16x8*)&Os[row * 264 + col] = *(const s16x8*)src;
    }

    for (int ct = 0; ct < 2; ++ct) {
        const int cg0 = (yh * 2 + ct) * 64;
        if (ct) __syncthreads();                 // Ws reuse guard
        stage_64x256(Ws, wproj_bf + (size_t)cg0 * NC, tid);
        __syncthreads();                         // Ws (and on ct==0, Os) visible

        bf16x8 a[8];
        #pragma unroll
        for (int kt = 0; kt < 8; ++kt)
            a[kt] = *(const bf16x8*)&Ws[(16 * w + c) * 264 + kt * 32 + q4 * 8];

        f32x4 acc[4];
        #pragma unroll
        for (int nt = 0; nt < 4; ++nt)
            #pragma unroll
            for (int r = 0; r < 4; ++r) acc[nt][r] = 0.f;

        #pragma unroll
        for (int nt = 0; nt < 4; ++nt)
            #pragma unroll
            for (int kt = 0; kt < 8; ++kt) {
                const bf16x8 bb = *(const bf16x8*)&Os[(16 * nt + c) * 264 + kt * 32 + q4 * 8];
                acc[nt] = __builtin_amdgcn_mfma_f32_16x16x32_bf16(a[kt], bb, acc[nt], 0, 0, 0);
            }

        #pragma unroll
        for (int nt = 0; nt < 4; ++nt)
            #pragma unroll
            for (int r = 0; r < 4; ++r) {
                const int cg = cg0 + 16 * w + 4 * q4 + r;
                out[((size_t)b * NC + cg) * NT + n0 + 16 * nt + c] = acc[nt][r] + b_proj[cg];
            }
    }
}

// ---------------------------------------------------------------------------
extern "C" void kernel_launch(void* const* d_in, const int* in_sizes, int n_in,
                              void* d_out, int out_size, void* d_ws, size_t ws_size,
                              hipStream_t stream)
{
    const float* x      = (const float*)d_in[0];
    const float* ln_g   = (const float*)d_in[1];
    const float* ln_b   = (const float*)d_in[2];
    const float* w_qkv  = (const float*)d_in[3];
    const float* w_proj = (const float*)d_in[4];
    const float* b_proj = (const float*)d_in[5];
    float* out = (float*)d_out;

    const size_t TEN = (size_t)NB * NHEADS * NT * DH;   // 4,194,304 elements

    unsigned short* ws16 = (unsigned short*)d_ws;
    unsigned short* q_bf    = ws16;
    unsigned short* k_bf    = ws16 + TEN;
    unsigned short* v_bf    = ws16 + 2 * TEN;
    unsigned short* o_bf    = ws16 + 3 * TEN;
    unsigned short* wqkv_t  = ws16 + 4 * TEN;            // [768][256]
    unsigned short* wproj_b = wqkv_t + 768 * 256;        // [256][256]

    k_prep<<<80, 256, 0, stream>>>(w_qkv, w_proj, wqkv_t, wproj_b);
    k_ln_qkv<<<NB * 64, 256, 0, stream>>>(x, ln_g, ln_b, wqkv_t, q_bf, k_bf, v_bf);
    k_attn<<<512, 256, 0, stream>>>(q_bf, k_bf, v_bf, o_bf);
    k_proj<<<dim3(NB * 64, 2), 256, 0, stream>>>(o_bf, wproj_b, b_proj, out);
}